// Round 8
// baseline (1393.488 us; speedup 1.0000x reference)
//
#include <hip/hip_runtime.h>
#include <math.h>

#define N_NODES 100000
#define E_EDGES 1600000
#define S_SNAP  4
#define D_IN    128
#define H_DIM   256
#define P_POST  10000
#define SCAN_NBLK ((N_NODES + 255) / 256)   // 391
#define NBIN 8
#define BIN_W (N_NODES / NBIN)              // 12500
#define FILL_CHUNK 2048
#define FILL_NCHUNK ((E_EDGES + FILL_CHUNK - 1) / FILL_CHUNK)   // 782

typedef __attribute__((ext_vector_type(8))) short bf16x8;   // MFMA A/B frag (4 VGPRs)
typedef __attribute__((ext_vector_type(4))) float f32x4;    // MFMA C/D frag

// ---------- bf16 helpers ----------
__device__ __forceinline__ float bf2f(unsigned short u) {
    union { unsigned int i; float f; } v; v.i = ((unsigned int)u) << 16; return v.f;
}
__device__ __forceinline__ unsigned short f2bf(float f) {
    union { float f; unsigned int i; } v; v.f = f;
    unsigned int lsb = (v.i >> 16) & 1u;
    v.i += 0x7fffu + lsb;                 // round-nearest-even
    return (unsigned short)(v.i >> 16);
}

// ---------------- utility ----------------
__global__ void zero32_kernel(unsigned int* __restrict__ p, int n) {
    int i = blockIdx.x * blockDim.x + threadIdx.x;
    if (i < n) p[i] = 0u;
}

// ---------------- graph prep ----------------
__global__ void hist_kernel(const int* __restrict__ dst, int* __restrict__ deg,
        int* __restrict__ slot) {
    int i = blockIdx.x * blockDim.x + threadIdx.x;
    if (i < E_EDGES) slot[i] = atomicAdd(&deg[dst[i]], 1);
}

__global__ void dinv_kernel(const int* __restrict__ deg, float* __restrict__ dinv) {
    int i = blockIdx.x * blockDim.x + threadIdx.x;
    if (i < N_NODES) dinv[i] = rsqrtf((float)(deg[i] + 1));  // +1 self-loop
}

__global__ __launch_bounds__(256) void scan_part_kernel(const int* __restrict__ deg,
        int* __restrict__ bsum) {
    __shared__ int red[4];
    int i = blockIdx.x * 256 + threadIdx.x;
    int s = (i < N_NODES) ? deg[i] : 0;
    #pragma unroll
    for (int off = 32; off > 0; off >>= 1) s += __shfl_down(s, off, 64);
    int wave = threadIdx.x >> 6, lane = threadIdx.x & 63;
    if (lane == 0) red[wave] = s;
    __syncthreads();
    if (threadIdx.x == 0) bsum[blockIdx.x] = red[0] + red[1] + red[2] + red[3];
}

__global__ __launch_bounds__(512) void scan_top_kernel(const int* __restrict__ bsum,
        int* __restrict__ boff) {
    __shared__ int s[512];
    int t = threadIdx.x;
    s[t] = (t < SCAN_NBLK) ? bsum[t] : 0;
    __syncthreads();
    for (int off = 1; off < 512; off <<= 1) {
        int v = (t >= off) ? s[t - off] : 0;
        __syncthreads();
        s[t] += v;
        __syncthreads();
    }
    if (t < SCAN_NBLK) boff[t] = (t == 0) ? 0 : s[t - 1];
}

__global__ __launch_bounds__(256) void scan_fin_kernel(const int* __restrict__ deg,
        const int* __restrict__ boff, int* __restrict__ rowptr) {
    __shared__ int s[256];
    int b = blockIdx.x, t = threadIdx.x;
    int i = b * 256 + t;
    int v = (i < N_NODES) ? deg[i] : 0;
    s[t] = v;
    __syncthreads();
    for (int off = 1; off < 256; off <<= 1) {
        int u = (t >= off) ? s[t - off] : 0;
        __syncthreads();
        s[t] += u;
        __syncthreads();
    }
    if (i < N_NODES) rowptr[i] = boff[b] + s[t] - v;   // exclusive
    if (i == 0) rowptr[N_NODES] = E_EDGES;
}

// binned, atomic-free CSR fill (each bin's 800KB region stays L2-resident)
__global__ __launch_bounds__(256) void fill_kernel(const int* __restrict__ src,
        const int* __restrict__ dst, const int* __restrict__ slot,
        const int* __restrict__ rowptr, int* __restrict__ csrsrc) {
    int chunk = blockIdx.x >> 3;
    int bin = blockIdx.x & (NBIN - 1);
    int lo = bin * BIN_W, hi = lo + BIN_W;
    int base = chunk * FILL_CHUNK + threadIdx.x;
    #pragma unroll
    for (int k = 0; k < FILL_CHUNK / 256; ++k) {
        int i = base + k * 256;
        if (i < E_EDGES) {
            int d = dst[i];
            if (d >= lo && d < hi) csrsrc[rowptr[d] + slot[i]] = src[i];
        }
    }
}

// ------- MFMA GEMM (once per call): xw1 = x @ W1, bf16 out -------
// K=128 in one LDS stage. Block: 64 rows x 64 cols, 4 waves; wave w = rows [16w,16w+16).
// Layouts (HW-verified, guide §3): A[m=lane&15][k=quad*8+j]; B[k=quad*8+j][n=lane&15];
// C/D: col=lane&15, row=quad*4+reg.
__global__ __launch_bounds__(256) void gemm_xw1_mfma(const float* __restrict__ A,
        const float* __restrict__ B, unsigned short* __restrict__ C, int M) {
    __shared__ unsigned short As[64][136];   // [m][k], +8 pad -> frag reads 2-way conflict (free)
    __shared__ unsigned short Bs[64][136];   // [n][k] (transposed on stage-in)
    int tid = threadIdx.x;
    int m0 = blockIdx.x * 64, n0 = blockIdx.y * 64;
    // stage A: thread t -> row t>>2, cols (t&3)*32..+32 (fp32 -> bf16)
    {
        int row = tid >> 2, c0 = (tid & 3) * 32;
        int gm = m0 + row;
        #pragma unroll
        for (int i = 0; i < 8; ++i) {
            float4 v = make_float4(0.f, 0.f, 0.f, 0.f);
            if (gm < M) v = *(const float4*)(A + (size_t)gm * D_IN + c0 + i * 4);
            As[row][c0 + i * 4 + 0] = f2bf(v.x);
            As[row][c0 + i * 4 + 1] = f2bf(v.y);
            As[row][c0 + i * 4 + 2] = f2bf(v.z);
            As[row][c0 + i * 4 + 3] = f2bf(v.w);
        }
    }
    // stage B transposed: thread t -> k = t>>1, n-range (t&1)*32..+32; Bs[n][k] = B[k][n0+n]
    {
        int k = tid >> 1, nb = (tid & 1) * 32;
        #pragma unroll
        for (int i = 0; i < 8; ++i) {
            float4 v = *(const float4*)(B + (size_t)k * H_DIM + n0 + nb + i * 4);
            Bs[nb + i * 4 + 0][k] = f2bf(v.x);
            Bs[nb + i * 4 + 1][k] = f2bf(v.y);
            Bs[nb + i * 4 + 2][k] = f2bf(v.z);
            Bs[nb + i * 4 + 3][k] = f2bf(v.w);
        }
    }
    __syncthreads();
    int w = tid >> 6, l = tid & 63;
    int q = l >> 4, mrow = l & 15;
    f32x4 acc[4] = {{0.f,0.f,0.f,0.f},{0.f,0.f,0.f,0.f},{0.f,0.f,0.f,0.f},{0.f,0.f,0.f,0.f}};
    #pragma unroll
    for (int kk = 0; kk < 4; ++kk) {                 // K-steps of 32
        bf16x8 a = *(const bf16x8*)&As[16 * w + mrow][kk * 32 + q * 8];
        #pragma unroll
        for (int ct = 0; ct < 4; ++ct) {             // 16-col tiles
            bf16x8 b = *(const bf16x8*)&Bs[ct * 16 + mrow][kk * 32 + q * 8];
            acc[ct] = __builtin_amdgcn_mfma_f32_16x16x32_bf16(a, b, acc[ct], 0, 0, 0);
        }
    }
    #pragma unroll
    for (int ct = 0; ct < 4; ++ct) {
        int col = n0 + ct * 16 + mrow;
        #pragma unroll
        for (int i = 0; i < 4; ++i) {
            int m = m0 + 16 * w + q * 4 + i;
            if (m < M) C[(size_t)m * H_DIM + col] = f2bf(acc[ct][i]);
        }
    }
}

// ------- SpMM layer 0 (fused bias+relu), 8-way edge unroll -------
__global__ __launch_bounds__(256) void spmm_l0_kernel(const unsigned short* __restrict__ xw1,
        const float* __restrict__ dinv, const int* __restrict__ rowptr,
        const int* __restrict__ csrsrc, const float* __restrict__ b1,
        unsigned short* __restrict__ h) {
    int r = (blockIdx.x << 2) + (threadIdx.x >> 6);
    int lane = threadIdx.x & 63;
    int e0 = rowptr[r], e1 = rowptr[r + 1];
    float di = dinv[r];
    float4 acc = make_float4(0.f, 0.f, 0.f, 0.f);
    const ushort4* tp = (const ushort4*)xw1;
    int e = e0;
    for (; e + 8 <= e1; e += 8) {
        int s[8]; float wv[8]; ushort4 u[8];
        #pragma unroll
        for (int j = 0; j < 8; ++j) s[j] = csrsrc[e + j];
        #pragma unroll
        for (int j = 0; j < 8; ++j) u[j] = tp[(size_t)s[j] * 64 + lane];
        #pragma unroll
        for (int j = 0; j < 8; ++j) wv[j] = dinv[s[j]] * di;
        #pragma unroll
        for (int j = 0; j < 8; ++j) {
            acc.x = fmaf(bf2f(u[j].x), wv[j], acc.x);
            acc.y = fmaf(bf2f(u[j].y), wv[j], acc.y);
            acc.z = fmaf(bf2f(u[j].z), wv[j], acc.z);
            acc.w = fmaf(bf2f(u[j].w), wv[j], acc.w);
        }
    }
    for (; e < e1; ++e) {
        int s = csrsrc[e];
        float wv = dinv[s] * di;
        ushort4 u = tp[(size_t)s * 64 + lane];
        acc.x = fmaf(bf2f(u.x), wv, acc.x); acc.y = fmaf(bf2f(u.y), wv, acc.y);
        acc.z = fmaf(bf2f(u.z), wv, acc.z); acc.w = fmaf(bf2f(u.w), wv, acc.w);
    }
    ushort4 us = tp[(size_t)r * 64 + lane];
    float wd = di * di;
    float4 bb = ((const float4*)b1)[lane];
    ushort4 o;
    o.x = f2bf(fmaxf(fmaf(bf2f(us.x), wd, acc.x) + bb.x, 0.f));
    o.y = f2bf(fmaxf(fmaf(bf2f(us.y), wd, acc.y) + bb.y, 0.f));
    o.z = f2bf(fmaxf(fmaf(bf2f(us.z), wd, acc.z) + bb.z, 0.f));
    o.w = f2bf(fmaxf(fmaf(bf2f(us.w), wd, acc.w) + bb.w, 0.f));
    ((ushort4*)h)[(size_t)r * 64 + lane] = o;
}

// ---------------- SpMM layer 1 (post rows only) ----------------
__global__ __launch_bounds__(256) void spmm_h_post_kernel(const unsigned short* __restrict__ h,
        const float* __restrict__ dinv, const int* __restrict__ rowptr,
        const int* __restrict__ csrsrc, const int* __restrict__ post,
        float* __restrict__ t1p) {
    int p = (blockIdx.x << 2) + (threadIdx.x >> 6);
    int lane = threadIdx.x & 63;
    int r = post[p];
    int e0 = rowptr[r], e1 = rowptr[r + 1];
    float di = dinv[r];
    float4 acc = make_float4(0.f, 0.f, 0.f, 0.f);
    const ushort4* hp = (const ushort4*)h;
    int e = e0;
    for (; e + 4 <= e1; e += 4) {
        int s0 = csrsrc[e], s1 = csrsrc[e + 1], s2 = csrsrc[e + 2], s3 = csrsrc[e + 3];
        float w0 = dinv[s0] * di, w1 = dinv[s1] * di, w2 = dinv[s2] * di, w3 = dinv[s3] * di;
        ushort4 u0 = hp[(size_t)s0 * 64 + lane];
        ushort4 u1 = hp[(size_t)s1 * 64 + lane];
        ushort4 u2 = hp[(size_t)s2 * 64 + lane];
        ushort4 u3 = hp[(size_t)s3 * 64 + lane];
        acc.x = fmaf(bf2f(u0.x), w0, acc.x); acc.y = fmaf(bf2f(u0.y), w0, acc.y);
        acc.z = fmaf(bf2f(u0.z), w0, acc.z); acc.w = fmaf(bf2f(u0.w), w0, acc.w);
        acc.x = fmaf(bf2f(u1.x), w1, acc.x); acc.y = fmaf(bf2f(u1.y), w1, acc.y);
        acc.z = fmaf(bf2f(u1.z), w1, acc.z); acc.w = fmaf(bf2f(u1.w), w1, acc.w);
        acc.x = fmaf(bf2f(u2.x), w2, acc.x); acc.y = fmaf(bf2f(u2.y), w2, acc.y);
        acc.z = fmaf(bf2f(u2.z), w2, acc.z); acc.w = fmaf(bf2f(u2.w), w2, acc.w);
        acc.x = fmaf(bf2f(u3.x), w3, acc.x); acc.y = fmaf(bf2f(u3.y), w3, acc.y);
        acc.z = fmaf(bf2f(u3.z), w3, acc.z); acc.w = fmaf(bf2f(u3.w), w3, acc.w);
    }
    for (; e < e1; ++e) {
        int s = csrsrc[e];
        float wv = dinv[s] * di;
        ushort4 u = hp[(size_t)s * 64 + lane];
        acc.x = fmaf(bf2f(u.x), wv, acc.x); acc.y = fmaf(bf2f(u.y), wv, acc.y);
        acc.z = fmaf(bf2f(u.z), wv, acc.z); acc.w = fmaf(bf2f(u.w), wv, acc.w);
    }
    ushort4 u = hp[(size_t)r * 64 + lane];
    float wd = di * di;
    acc.x = fmaf(bf2f(u.x), wd, acc.x);
    acc.y = fmaf(bf2f(u.y), wd, acc.y);
    acc.z = fmaf(bf2f(u.z), wd, acc.z);
    acc.w = fmaf(bf2f(u.w), wd, acc.w);
    ((float4*)t1p)[(size_t)p * 64 + lane] = acc;
}

// ------- GEMM layer 1 (post rows): accP += t1p @ W2 + b2 + h[post] -------
__global__ __launch_bounds__(256) void gemm_l1_kernel(const float* __restrict__ A,
        const float* __restrict__ B, const float* __restrict__ b2,
        const unsigned short* __restrict__ h, const int* __restrict__ post,
        float* __restrict__ accP, int M) {
    __shared__ float As[16][68];
    __shared__ float Bs[16][68];
    int tid = threadIdx.x;
    int tx = tid & 15, ty = tid >> 4;
    int m0 = blockIdx.x * 64, n0 = blockIdx.y * 64;
    int lar = tid >> 2;
    int lac = (tid & 3) << 2;
    int lbr = tid >> 4;
    int lbc = (tid & 15) << 2;
    float acc[4][4] = {};
    for (int kk = 0; kk < 256; kk += 16) {
        float4 av = make_float4(0.f, 0.f, 0.f, 0.f);
        if (m0 + lar < M) av = *(const float4*)(A + (size_t)(m0 + lar) * 256 + kk + lac);
        float4 bv = *(const float4*)(B + (size_t)(kk + lbr) * 256 + n0 + lbc);
        __syncthreads();
        As[lac + 0][lar] = av.x; As[lac + 1][lar] = av.y;
        As[lac + 2][lar] = av.z; As[lac + 3][lar] = av.w;
        *(float4*)(&Bs[lbr][lbc]) = bv;
        __syncthreads();
        #pragma unroll
        for (int k = 0; k < 16; ++k) {
            float4 a4 = *(const float4*)(&As[k][ty << 2]);
            float4 b4 = *(const float4*)(&Bs[k][tx << 2]);
            float a[4] = {a4.x, a4.y, a4.z, a4.w};
            float b[4] = {b4.x, b4.y, b4.z, b4.w};
            #pragma unroll
            for (int i = 0; i < 4; ++i)
                #pragma unroll
                for (int j = 0; j < 4; ++j)
                    acc[i][j] = fmaf(a[i], b[j], acc[i][j]);
        }
    }
    int nb = n0 + (tx << 2);
    float4 bv = *(const float4*)(b2 + nb);
    float bf[4] = {bv.x, bv.y, bv.z, bv.w};
    #pragma unroll
    for (int i = 0; i < 4; ++i) {
        int m = m0 + (ty << 2) + i;
        if (m < M) {
            int node = post[m];
            ushort4 hr = *(const ushort4*)(h + (size_t)node * 256 + nb);
            float4 a = *(float4*)(accP + (size_t)m * 256 + nb);
            a.x += acc[i][0] + bf[0] + bf2f(hr.x);
            a.y += acc[i][1] + bf[1] + bf2f(hr.y);
            a.z += acc[i][2] + bf[2] + bf2f(hr.z);
            a.w += acc[i][3] + bf[3] + bf2f(hr.w);
            *(float4*)(accP + (size_t)m * 256 + nb) = a;
        }
    }
}

// ---------------- classifier ----------------
__global__ __launch_bounds__(128) void classifier_kernel(const float* __restrict__ accP,
        const float* __restrict__ Wc1, const float* __restrict__ bc1,
        const float* __restrict__ Wc2, const float* __restrict__ bc2,
        float* __restrict__ out) {
    __shared__ float arow[8][256];
    __shared__ float red[2][8];
    int p0 = blockIdx.x << 3;
    int tid = threadIdx.x;
    for (int idx = tid; idx < 8 * 256; idx += 128) {
        int pl = idx >> 8, k = idx & 255;
        arow[pl][k] = 0.25f * accP[(size_t)(p0 + pl) * 256 + k];
    }
    __syncthreads();
    float s[8];
    float b = bc1[tid];
    #pragma unroll
    for (int pl = 0; pl < 8; ++pl) s[pl] = b;
    for (int k = 0; k < 256; ++k) {
        float wv = Wc1[k * 128 + tid];
        #pragma unroll
        for (int pl = 0; pl < 8; ++pl) s[pl] = fmaf(arow[pl][k], wv, s[pl]);
    }
    float wc2 = Wc2[tid];
    float part[8];
    #pragma unroll
    for (int pl = 0; pl < 8; ++pl) part[pl] = fmaxf(s[pl], 0.f) * wc2;
    #pragma unroll
    for (int off = 32; off > 0; off >>= 1)
        #pragma unroll
        for (int pl = 0; pl < 8; ++pl) part[pl] += __shfl_down(part[pl], off, 64);
    int wave = tid >> 6, lane = tid & 63;
    if (lane == 0) {
        #pragma unroll
        for (int pl = 0; pl < 8; ++pl) red[wave][pl] = part[pl];
    }
    __syncthreads();
    if (tid < 8) {
        float logit = red[0][tid] + red[1][tid] + bc2[0];
        out[p0 + tid] = 1.f / (1.f + expf(-logit));
    }
}

extern "C" void kernel_launch(void* const* d_in, const int* in_sizes, int n_in,
                              void* d_out, int out_size, void* d_ws, size_t ws_size,
                              hipStream_t stream) {
    const float* x   = (const float*)d_in[0];
    const int*   ei  = (const int*)d_in[1];
    const int*   post= (const int*)d_in[2];
    const float* W1  = (const float*)d_in[3];
    const float* b1  = (const float*)d_in[4];
    const float* W2  = (const float*)d_in[5];
    const float* b2  = (const float*)d_in[6];
    const float* Wc1 = (const float*)d_in[7];
    const float* bc1 = (const float*)d_in[8];
    const float* Wc2 = (const float*)d_in[9];
    const float* bc2 = (const float*)d_in[10];
    float* out = (float*)d_out;

    char* w = (char*)d_ws;
    size_t off = 0;
#define WS_ALLOC(type, name, count) \
    type* name = (type*)(w + off); \
    off += (((size_t)(count) * sizeof(type)) + 255) & ~(size_t)255;
    WS_ALLOC(unsigned short, xw1,  (size_t)N_NODES * H_DIM)   // 51.2 MB (bf16)
    WS_ALLOC(unsigned short, hbuf, (size_t)N_NODES * H_DIM)   // 51.2 MB (bf16)
    WS_ALLOC(float,          t1p,  (size_t)P_POST * H_DIM)    // 10.24 MB (aliased by slot)
    WS_ALLOC(float,          accP, (size_t)P_POST * H_DIM)    // 10.24 MB
    WS_ALLOC(int,            deg,    N_NODES)
    WS_ALLOC(float,          dinvb,  N_NODES)
    WS_ALLOC(int,            rowptr, N_NODES + 1)
    WS_ALLOC(int,            csrsrc, E_EDGES)                 // 6.4 MB -> total ~131 MB
    WS_ALLOC(int,            bsum,   SCAN_NBLK)
    WS_ALLOC(int,            boff,   SCAN_NBLK)
#undef WS_ALLOC
    int* slot = (int*)t1p;   // slot aliases t1p (dead when t1p is written)
    (void)ws_size; (void)in_sizes; (void)n_in; (void)out_size;

    zero32_kernel<<<(P_POST * H_DIM + 255) / 256, 256, 0, stream>>>((unsigned int*)accP, P_POST * H_DIM);

    // xw1 = x @ W1 once per call (snapshot-invariant) — bf16 MFMA
    dim3 gg((N_NODES + 63) / 64, H_DIM / 64);
    gemm_xw1_mfma<<<gg, 256, 0, stream>>>(x, W1, xw1, N_NODES);

    for (int s = 0; s < S_SNAP; ++s) {
        const int* srcs = ei + (size_t)s * 2 * E_EDGES;
        const int* dsts = srcs + E_EDGES;
        zero32_kernel<<<(N_NODES + 255) / 256, 256, 0, stream>>>((unsigned int*)deg, N_NODES);
        hist_kernel<<<E_EDGES / 256, 256, 0, stream>>>(dsts, deg, slot);
        dinv_kernel<<<(N_NODES + 255) / 256, 256, 0, stream>>>(deg, dinvb);
        scan_part_kernel<<<SCAN_NBLK, 256, 0, stream>>>(deg, bsum);
        scan_top_kernel<<<1, 512, 0, stream>>>(bsum, boff);
        scan_fin_kernel<<<SCAN_NBLK, 256, 0, stream>>>(deg, boff, rowptr);
        fill_kernel<<<FILL_NCHUNK * NBIN, 256, 0, stream>>>(srcs, dsts, slot, rowptr, csrsrc);
        // h = relu(Ahat @ xw1 + b1)   [N,256] bf16
        spmm_l0_kernel<<<N_NODES / 4, 256, 0, stream>>>(xw1, dinvb, rowptr, csrsrc, b1, hbuf);
        // t1p = (Ahat @ h)[post]   [P,256] fp32
        spmm_h_post_kernel<<<P_POST / 4, 256, 0, stream>>>(hbuf, dinvb, rowptr, csrsrc, post, t1p);
        // accP += t1p @ W2 + b2 + h[post]
        dim3 g1((P_POST + 63) / 64, 4);
        gemm_l1_kernel<<<g1, 256, 0, stream>>>(t1p, W2, b2, hbuf, post, accP, P_POST);
    }
    classifier_kernel<<<P_POST / 8, 128, 0, stream>>>(accP, Wc1, bc1, Wc2, bc2, out);
}

// Round 9
// 1331.993 us; speedup vs baseline: 1.0462x; 1.0462x over previous
//
#include <hip/hip_runtime.h>
#include <math.h>

#define N_NODES 100000
#define E_EDGES 1600000
#define S_SNAP  4
#define D_IN    128
#define H_DIM   256
#define P_POST  10000
#define SCAN_NBLK ((N_NODES + 255) / 256)   // 391
#define NBIN 8
#define BIN_W (N_NODES / NBIN)              // 12500
#define FILL_CHUNK 2048
#define FILL_NCHUNK ((E_EDGES + FILL_CHUNK - 1) / FILL_CHUNK)   // 782

typedef __attribute__((ext_vector_type(8))) short bf16x8;   // MFMA A/B frag (4 VGPRs)
typedef __attribute__((ext_vector_type(4))) float f32x4;    // MFMA C/D frag

// ---------- bf16 helpers ----------
__device__ __forceinline__ float bf2f(unsigned short u) {
    union { unsigned int i; float f; } v; v.i = ((unsigned int)u) << 16; return v.f;
}
__device__ __forceinline__ unsigned short f2bf(float f) {
    union { float f; unsigned int i; } v; v.f = f;
    unsigned int lsb = (v.i >> 16) & 1u;
    v.i += 0x7fffu + lsb;                 // round-nearest-even
    return (unsigned short)(v.i >> 16);
}

// ---------------- utility ----------------
__global__ void zero32_kernel(unsigned int* __restrict__ p, int n) {
    int i = blockIdx.x * blockDim.x + threadIdx.x;
    if (i < n) p[i] = 0u;
}

// ---------------- graph prep ----------------
__global__ void hist_kernel(const int* __restrict__ dst, int* __restrict__ deg,
        int* __restrict__ slot) {
    int i = blockIdx.x * blockDim.x + threadIdx.x;
    if (i < E_EDGES) slot[i] = atomicAdd(&deg[dst[i]], 1);
}

// scan phase 1; also emits dinv (fused — reads deg anyway)
__global__ __launch_bounds__(256) void scan_part_kernel(const int* __restrict__ deg,
        int* __restrict__ bsum, float* __restrict__ dinv) {
    __shared__ int red[4];
    int i = blockIdx.x * 256 + threadIdx.x;
    int s = 0;
    if (i < N_NODES) {
        s = deg[i];
        dinv[i] = rsqrtf((float)(s + 1));   // +1 self-loop
    }
    int t = s;
    #pragma unroll
    for (int off = 32; off > 0; off >>= 1) t += __shfl_down(t, off, 64);
    int wave = threadIdx.x >> 6, lane = threadIdx.x & 63;
    if (lane == 0) red[wave] = t;
    __syncthreads();
    if (threadIdx.x == 0) bsum[blockIdx.x] = red[0] + red[1] + red[2] + red[3];
}

__global__ __launch_bounds__(512) void scan_top_kernel(const int* __restrict__ bsum,
        int* __restrict__ boff) {
    __shared__ int s[512];
    int t = threadIdx.x;
    s[t] = (t < SCAN_NBLK) ? bsum[t] : 0;
    __syncthreads();
    for (int off = 1; off < 512; off <<= 1) {
        int v = (t >= off) ? s[t - off] : 0;
        __syncthreads();
        s[t] += v;
        __syncthreads();
    }
    if (t < SCAN_NBLK) boff[t] = (t == 0) ? 0 : s[t - 1];
}

__global__ __launch_bounds__(256) void scan_fin_kernel(const int* __restrict__ deg,
        const int* __restrict__ boff, int* __restrict__ rowptr) {
    __shared__ int s[256];
    int b = blockIdx.x, t = threadIdx.x;
    int i = b * 256 + t;
    int v = (i < N_NODES) ? deg[i] : 0;
    s[t] = v;
    __syncthreads();
    for (int off = 1; off < 256; off <<= 1) {
        int u = (t >= off) ? s[t - off] : 0;
        __syncthreads();
        s[t] += u;
        __syncthreads();
    }
    if (i < N_NODES) rowptr[i] = boff[b] + s[t] - v;   // exclusive
    if (i == 0) rowptr[N_NODES] = E_EDGES;
}

// binned, atomic-free CSR fill (each bin's 800KB region stays L2-resident)
__global__ __launch_bounds__(256) void fill_kernel(const int* __restrict__ src,
        const int* __restrict__ dst, const int* __restrict__ slot,
        const int* __restrict__ rowptr, int* __restrict__ csrsrc) {
    int chunk = blockIdx.x >> 3;
    int bin = blockIdx.x & (NBIN - 1);
    int lo = bin * BIN_W, hi = lo + BIN_W;
    int base = chunk * FILL_CHUNK + threadIdx.x;
    #pragma unroll
    for (int k = 0; k < FILL_CHUNK / 256; ++k) {
        int i = base + k * 256;
        if (i < E_EDGES) {
            int d = dst[i];
            if (d >= lo && d < hi) csrsrc[rowptr[d] + slot[i]] = src[i];
        }
    }
}

// ------- MFMA GEMM (once per call): xw1 = x @ W1, bf16 out -------
// Layouts (HW-verified r8): A[m=lane&15][k=quad*8+j]; B[k][n=lane&15]; C/D col=lane&15,row=quad*4+reg
__global__ __launch_bounds__(256) void gemm_xw1_mfma(const float* __restrict__ A,
        const float* __restrict__ B, unsigned short* __restrict__ C, int M) {
    __shared__ unsigned short As[64][136];   // [m][k], +8 pad
    __shared__ unsigned short Bs[64][136];   // [n][k]
    int tid = threadIdx.x;
    int m0 = blockIdx.x * 64, n0 = blockIdx.y * 64;
    {
        int row = tid >> 2, c0 = (tid & 3) * 32;
        int gm = m0 + row;
        #pragma unroll
        for (int i = 0; i < 8; ++i) {
            float4 v = make_float4(0.f, 0.f, 0.f, 0.f);
            if (gm < M) v = *(const float4*)(A + (size_t)gm * D_IN + c0 + i * 4);
            As[row][c0 + i * 4 + 0] = f2bf(v.x);
            As[row][c0 + i * 4 + 1] = f2bf(v.y);
            As[row][c0 + i * 4 + 2] = f2bf(v.z);
            As[row][c0 + i * 4 + 3] = f2bf(v.w);
        }
    }
    {
        int k = tid >> 1, nb = (tid & 1) * 32;
        #pragma unroll
        for (int i = 0; i < 8; ++i) {
            float4 v = *(const float4*)(B + (size_t)k * H_DIM + n0 + nb + i * 4);
            Bs[nb + i * 4 + 0][k] = f2bf(v.x);
            Bs[nb + i * 4 + 1][k] = f2bf(v.y);
            Bs[nb + i * 4 + 2][k] = f2bf(v.z);
            Bs[nb + i * 4 + 3][k] = f2bf(v.w);
        }
    }
    __syncthreads();
    int w = tid >> 6, l = tid & 63;
    int q = l >> 4, mrow = l & 15;
    f32x4 acc[4] = {{0.f,0.f,0.f,0.f},{0.f,0.f,0.f,0.f},{0.f,0.f,0.f,0.f},{0.f,0.f,0.f,0.f}};
    #pragma unroll
    for (int kk = 0; kk < 4; ++kk) {
        bf16x8 a = *(const bf16x8*)&As[16 * w + mrow][kk * 32 + q * 8];
        #pragma unroll
        for (int ct = 0; ct < 4; ++ct) {
            bf16x8 b = *(const bf16x8*)&Bs[ct * 16 + mrow][kk * 32 + q * 8];
            acc[ct] = __builtin_amdgcn_mfma_f32_16x16x32_bf16(a, b, acc[ct], 0, 0, 0);
        }
    }
    #pragma unroll
    for (int ct = 0; ct < 4; ++ct) {
        int col = n0 + ct * 16 + mrow;
        #pragma unroll
        for (int i = 0; i < 4; ++i) {
            int m = m0 + 16 * w + q * 4 + i;
            if (m < M) C[(size_t)m * H_DIM + col] = f2bf(acc[ct][i]);
        }
    }
}

// ------- SpMM layer 0 (fused bias+relu), 4-way edge unroll (r7-proven: VGPR 20, occ 75%) ---
__global__ __launch_bounds__(256) void spmm_l0_kernel(const unsigned short* __restrict__ xw1,
        const float* __restrict__ dinv, const int* __restrict__ rowptr,
        const int* __restrict__ csrsrc, const float* __restrict__ b1,
        unsigned short* __restrict__ h) {
    int r = (blockIdx.x << 2) + (threadIdx.x >> 6);
    int lane = threadIdx.x & 63;
    int e0 = rowptr[r], e1 = rowptr[r + 1];
    float di = dinv[r];
    float4 acc = make_float4(0.f, 0.f, 0.f, 0.f);
    const ushort4* tp = (const ushort4*)xw1;
    int e = e0;
    for (; e + 4 <= e1; e += 4) {
        int s0 = csrsrc[e], s1 = csrsrc[e + 1], s2 = csrsrc[e + 2], s3 = csrsrc[e + 3];
        float w0 = dinv[s0] * di, w1 = dinv[s1] * di, w2 = dinv[s2] * di, w3 = dinv[s3] * di;
        ushort4 u0 = tp[(size_t)s0 * 64 + lane];
        ushort4 u1 = tp[(size_t)s1 * 64 + lane];
        ushort4 u2 = tp[(size_t)s2 * 64 + lane];
        ushort4 u3 = tp[(size_t)s3 * 64 + lane];
        acc.x = fmaf(bf2f(u0.x), w0, acc.x); acc.y = fmaf(bf2f(u0.y), w0, acc.y);
        acc.z = fmaf(bf2f(u0.z), w0, acc.z); acc.w = fmaf(bf2f(u0.w), w0, acc.w);
        acc.x = fmaf(bf2f(u1.x), w1, acc.x); acc.y = fmaf(bf2f(u1.y), w1, acc.y);
        acc.z = fmaf(bf2f(u1.z), w1, acc.z); acc.w = fmaf(bf2f(u1.w), w1, acc.w);
        acc.x = fmaf(bf2f(u2.x), w2, acc.x); acc.y = fmaf(bf2f(u2.y), w2, acc.y);
        acc.z = fmaf(bf2f(u2.z), w2, acc.z); acc.w = fmaf(bf2f(u2.w), w2, acc.w);
        acc.x = fmaf(bf2f(u3.x), w3, acc.x); acc.y = fmaf(bf2f(u3.y), w3, acc.y);
        acc.z = fmaf(bf2f(u3.z), w3, acc.z); acc.w = fmaf(bf2f(u3.w), w3, acc.w);
    }
    for (; e < e1; ++e) {
        int s = csrsrc[e];
        float wv = dinv[s] * di;
        ushort4 u = tp[(size_t)s * 64 + lane];
        acc.x = fmaf(bf2f(u.x), wv, acc.x); acc.y = fmaf(bf2f(u.y), wv, acc.y);
        acc.z = fmaf(bf2f(u.z), wv, acc.z); acc.w = fmaf(bf2f(u.w), wv, acc.w);
    }
    ushort4 us = tp[(size_t)r * 64 + lane];
    float wd = di * di;
    float4 bb = ((const float4*)b1)[lane];
    ushort4 o;
    o.x = f2bf(fmaxf(fmaf(bf2f(us.x), wd, acc.x) + bb.x, 0.f));
    o.y = f2bf(fmaxf(fmaf(bf2f(us.y), wd, acc.y) + bb.y, 0.f));
    o.z = f2bf(fmaxf(fmaf(bf2f(us.z), wd, acc.z) + bb.z, 0.f));
    o.w = f2bf(fmaxf(fmaf(bf2f(us.w), wd, acc.w) + bb.w, 0.f));
    ((ushort4*)h)[(size_t)r * 64 + lane] = o;
}

// ---------------- SpMM layer 1 (post rows only) ----------------
__global__ __launch_bounds__(256) void spmm_h_post_kernel(const unsigned short* __restrict__ h,
        const float* __restrict__ dinv, const int* __restrict__ rowptr,
        const int* __restrict__ csrsrc, const int* __restrict__ post,
        float* __restrict__ t1p) {
    int p = (blockIdx.x << 2) + (threadIdx.x >> 6);
    int lane = threadIdx.x & 63;
    int r = post[p];
    int e0 = rowptr[r], e1 = rowptr[r + 1];
    float di = dinv[r];
    float4 acc = make_float4(0.f, 0.f, 0.f, 0.f);
    const ushort4* hp = (const ushort4*)h;
    int e = e0;
    for (; e + 4 <= e1; e += 4) {
        int s0 = csrsrc[e], s1 = csrsrc[e + 1], s2 = csrsrc[e + 2], s3 = csrsrc[e + 3];
        float w0 = dinv[s0] * di, w1 = dinv[s1] * di, w2 = dinv[s2] * di, w3 = dinv[s3] * di;
        ushort4 u0 = hp[(size_t)s0 * 64 + lane];
        ushort4 u1 = hp[(size_t)s1 * 64 + lane];
        ushort4 u2 = hp[(size_t)s2 * 64 + lane];
        ushort4 u3 = hp[(size_t)s3 * 64 + lane];
        acc.x = fmaf(bf2f(u0.x), w0, acc.x); acc.y = fmaf(bf2f(u0.y), w0, acc.y);
        acc.z = fmaf(bf2f(u0.z), w0, acc.z); acc.w = fmaf(bf2f(u0.w), w0, acc.w);
        acc.x = fmaf(bf2f(u1.x), w1, acc.x); acc.y = fmaf(bf2f(u1.y), w1, acc.y);
        acc.z = fmaf(bf2f(u1.z), w1, acc.z); acc.w = fmaf(bf2f(u1.w), w1, acc.w);
        acc.x = fmaf(bf2f(u2.x), w2, acc.x); acc.y = fmaf(bf2f(u2.y), w2, acc.y);
        acc.z = fmaf(bf2f(u2.z), w2, acc.z); acc.w = fmaf(bf2f(u2.w), w2, acc.w);
        acc.x = fmaf(bf2f(u3.x), w3, acc.x); acc.y = fmaf(bf2f(u3.y), w3, acc.y);
        acc.z = fmaf(bf2f(u3.z), w3, acc.z); acc.w = fmaf(bf2f(u3.w), w3, acc.w);
    }
    for (; e < e1; ++e) {
        int s = csrsrc[e];
        float wv = dinv[s] * di;
        ushort4 u = hp[(size_t)s * 64 + lane];
        acc.x = fmaf(bf2f(u.x), wv, acc.x); acc.y = fmaf(bf2f(u.y), wv, acc.y);
        acc.z = fmaf(bf2f(u.z), wv, acc.z); acc.w = fmaf(bf2f(u.w), wv, acc.w);
    }
    ushort4 u = hp[(size_t)r * 64 + lane];
    float wd = di * di;
    acc.x = fmaf(bf2f(u.x), wd, acc.x);
    acc.y = fmaf(bf2f(u.y), wd, acc.y);
    acc.z = fmaf(bf2f(u.z), wd, acc.z);
    acc.w = fmaf(bf2f(u.w), wd, acc.w);
    ((float4*)t1p)[(size_t)p * 64 + lane] = acc;
}

// ------- MFMA GEMM layer 1 (post rows): accP += t1p @ W2 + b2 + h[post] -------
// K=256 in 2 LDS stages of 128; same verified fragment layouts as gemm_xw1_mfma.
__global__ __launch_bounds__(256) void gemm_l1_mfma(const float* __restrict__ A,
        const float* __restrict__ B, const float* __restrict__ b2,
        const unsigned short* __restrict__ h, const int* __restrict__ post,
        float* __restrict__ accP, int M) {
    __shared__ unsigned short As[64][136];
    __shared__ unsigned short Bs[64][136];
    int tid = threadIdx.x;
    int m0 = blockIdx.x * 64, n0 = blockIdx.y * 64;
    int w = tid >> 6, l = tid & 63;
    int q = l >> 4, mrow = l & 15;
    f32x4 acc[4] = {{0.f,0.f,0.f,0.f},{0.f,0.f,0.f,0.f},{0.f,0.f,0.f,0.f},{0.f,0.f,0.f,0.f}};
    for (int kk = 0; kk < 256; kk += 128) {
        __syncthreads();
        {
            int row = tid >> 2, c0 = (tid & 3) * 32;
            int gm = m0 + row;
            #pragma unroll
            for (int i = 0; i < 8; ++i) {
                float4 v = make_float4(0.f, 0.f, 0.f, 0.f);
                if (gm < M) v = *(const float4*)(A + (size_t)gm * 256 + kk + c0 + i * 4);
                As[row][c0 + i * 4 + 0] = f2bf(v.x);
                As[row][c0 + i * 4 + 1] = f2bf(v.y);
                As[row][c0 + i * 4 + 2] = f2bf(v.z);
                As[row][c0 + i * 4 + 3] = f2bf(v.w);
            }
        }
        {
            int k = tid >> 1, nb = (tid & 1) * 32;
            #pragma unroll
            for (int i = 0; i < 8; ++i) {
                float4 v = *(const float4*)(B + (size_t)(kk + k) * H_DIM + n0 + nb + i * 4);
                Bs[nb + i * 4 + 0][k] = f2bf(v.x);
                Bs[nb + i * 4 + 1][k] = f2bf(v.y);
                Bs[nb + i * 4 + 2][k] = f2bf(v.z);
                Bs[nb + i * 4 + 3][k] = f2bf(v.w);
            }
        }
        __syncthreads();
        #pragma unroll
        for (int ks = 0; ks < 4; ++ks) {
            bf16x8 a = *(const bf16x8*)&As[16 * w + mrow][ks * 32 + q * 8];
            #pragma unroll
            for (int ct = 0; ct < 4; ++ct) {
                bf16x8 b = *(const bf16x8*)&Bs[ct * 16 + mrow][ks * 32 + q * 8];
                acc[ct] = __builtin_amdgcn_mfma_f32_16x16x32_bf16(a, b, acc[ct], 0, 0, 0);
            }
        }
    }
    #pragma unroll
    for (int ct = 0; ct < 4; ++ct) {
        int col = n0 + ct * 16 + mrow;
        float bias = b2[col];
        #pragma unroll
        for (int i = 0; i < 4; ++i) {
            int m = m0 + 16 * w + q * 4 + i;
            if (m < M) {
                int node = post[m];
                float hv = bf2f(h[(size_t)node * 256 + col]);
                accP[(size_t)m * 256 + col] += acc[ct][i] + bias + hv;
            }
        }
    }
}

// ---------------- classifier ----------------
__global__ __launch_bounds__(128) void classifier_kernel(const float* __restrict__ accP,
        const float* __restrict__ Wc1, const float* __restrict__ bc1,
        const float* __restrict__ Wc2, const float* __restrict__ bc2,
        float* __restrict__ out) {
    __shared__ float arow[8][256];
    __shared__ float red[2][8];
    int p0 = blockIdx.x << 3;
    int tid = threadIdx.x;
    for (int idx = tid; idx < 8 * 256; idx += 128) {
        int pl = idx >> 8, k = idx & 255;
        arow[pl][k] = 0.25f * accP[(size_t)(p0 + pl) * 256 + k];
    }
    __syncthreads();
    float s[8];
    float b = bc1[tid];
    #pragma unroll
    for (int pl = 0; pl < 8; ++pl) s[pl] = b;
    for (int k = 0; k < 256; ++k) {
        float wv = Wc1[k * 128 + tid];
        #pragma unroll
        for (int pl = 0; pl < 8; ++pl) s[pl] = fmaf(arow[pl][k], wv, s[pl]);
    }
    float wc2 = Wc2[tid];
    float part[8];
    #pragma unroll
    for (int pl = 0; pl < 8; ++pl) part[pl] = fmaxf(s[pl], 0.f) * wc2;
    #pragma unroll
    for (int off = 32; off > 0; off >>= 1)
        #pragma unroll
        for (int pl = 0; pl < 8; ++pl) part[pl] += __shfl_down(part[pl], off, 64);
    int wave = tid >> 6, lane = tid & 63;
    if (lane == 0) {
        #pragma unroll
        for (int pl = 0; pl < 8; ++pl) red[wave][pl] = part[pl];
    }
    __syncthreads();
    if (tid < 8) {
        float logit = red[0][tid] + red[1][tid] + bc2[0];
        out[p0 + tid] = 1.f / (1.f + expf(-logit));
    }
}

extern "C" void kernel_launch(void* const* d_in, const int* in_sizes, int n_in,
                              void* d_out, int out_size, void* d_ws, size_t ws_size,
                              hipStream_t stream) {
    const float* x   = (const float*)d_in[0];
    const int*   ei  = (const int*)d_in[1];
    const int*   post= (const int*)d_in[2];
    const float* W1  = (const float*)d_in[3];
    const float* b1  = (const float*)d_in[4];
    const float* W2  = (const float*)d_in[5];
    const float* b2  = (const float*)d_in[6];
    const float* Wc1 = (const float*)d_in[7];
    const float* bc1 = (const float*)d_in[8];
    const float* Wc2 = (const float*)d_in[9];
    const float* bc2 = (const float*)d_in[10];
    float* out = (float*)d_out;

    char* w = (char*)d_ws;
    size_t off = 0;
#define WS_ALLOC(type, name, count) \
    type* name = (type*)(w + off); \
    off += (((size_t)(count) * sizeof(type)) + 255) & ~(size_t)255;
    WS_ALLOC(unsigned short, xw1,  (size_t)N_NODES * H_DIM)   // 51.2 MB (bf16)
    WS_ALLOC(unsigned short, hbuf, (size_t)N_NODES * H_DIM)   // 51.2 MB (bf16)
    WS_ALLOC(float,          t1p,  (size_t)P_POST * H_DIM)    // 10.24 MB (aliased by slot)
    WS_ALLOC(float,          accP, (size_t)P_POST * H_DIM)    // 10.24 MB
    WS_ALLOC(int,            deg,    N_NODES)
    WS_ALLOC(float,          dinvb,  N_NODES)
    WS_ALLOC(int,            rowptr, N_NODES + 1)
    WS_ALLOC(int,            csrsrc, E_EDGES)                 // 6.4 MB -> total ~131 MB
    WS_ALLOC(int,            bsum,   SCAN_NBLK)
    WS_ALLOC(int,            boff,   SCAN_NBLK)
#undef WS_ALLOC
    int* slot = (int*)t1p;   // slot aliases t1p (dead when t1p is written)
    (void)ws_size; (void)in_sizes; (void)n_in; (void)out_size;

    zero32_kernel<<<(P_POST * H_DIM + 255) / 256, 256, 0, stream>>>((unsigned int*)accP, P_POST * H_DIM);

    // xw1 = x @ W1 once per call (snapshot-invariant) — bf16 MFMA
    dim3 gg((N_NODES + 63) / 64, H_DIM / 64);
    gemm_xw1_mfma<<<gg, 256, 0, stream>>>(x, W1, xw1, N_NODES);

    for (int s = 0; s < S_SNAP; ++s) {
        const int* srcs = ei + (size_t)s * 2 * E_EDGES;
        const int* dsts = srcs + E_EDGES;
        zero32_kernel<<<(N_NODES + 255) / 256, 256, 0, stream>>>((unsigned int*)deg, N_NODES);
        hist_kernel<<<E_EDGES / 256, 256, 0, stream>>>(dsts, deg, slot);
        scan_part_kernel<<<SCAN_NBLK, 256, 0, stream>>>(deg, bsum, dinvb);  // dinv fused
        scan_top_kernel<<<1, 512, 0, stream>>>(bsum, boff);
        scan_fin_kernel<<<SCAN_NBLK, 256, 0, stream>>>(deg, boff, rowptr);
        fill_kernel<<<FILL_NCHUNK * NBIN, 256, 0, stream>>>(srcs, dsts, slot, rowptr, csrsrc);
        // h = relu(Ahat @ xw1 + b1)   [N,256] bf16
        spmm_l0_kernel<<<N_NODES / 4, 256, 0, stream>>>(xw1, dinvb, rowptr, csrsrc, b1, hbuf);
        // t1p = (Ahat @ h)[post]   [P,256] fp32
        spmm_h_post_kernel<<<P_POST / 4, 256, 0, stream>>>(hbuf, dinvb, rowptr, csrsrc, post, t1p);
        // accP += t1p @ W2 + b2 + h[post]   — bf16 MFMA
        dim3 g1((P_POST + 63) / 64, H_DIM / 64);
        gemm_l1_mfma<<<g1, 256, 0, stream>>>(t1p, W2, b2, hbuf, post, accP, P_POST);
    }
    classifier_kernel<<<P_POST / 8, 128, 0, stream>>>(accP, Wc1, bc1, Wc2, bc2, out);
}

// Round 10
// 1294.938 us; speedup vs baseline: 1.0761x; 1.0286x over previous
//
#include <hip/hip_runtime.h>
#include <math.h>

#define N_NODES 100000
#define E_EDGES 1600000
#define S_SNAP  4
#define D_IN    128
#define H_DIM   256
#define P_POST  10000
#define N4 (S_SNAP * N_NODES)               // 400000
#define E4 (S_SNAP * E_EDGES)               // 6400000
#define NBLK4 ((N4 + 1023) / 1024)          // 391 (block scans 1024 elems, int4/thread)
#define NBIN 8
#define BIN_W (N_NODES / NBIN)              // 12500
#define FILL_CHUNK 2048
#define FILL_NCHUNK ((E4 + FILL_CHUNK - 1) / FILL_CHUNK)   // 3125

typedef __attribute__((ext_vector_type(8))) short bf16x8;   // MFMA A/B frag (4 VGPRs)
typedef __attribute__((ext_vector_type(4))) float f32x4;    // MFMA C/D frag

// ---------- bf16 helpers ----------
__device__ __forceinline__ float bf2f(unsigned short u) {
    union { unsigned int i; float f; } v; v.i = ((unsigned int)u) << 16; return v.f;
}
__device__ __forceinline__ unsigned short f2bf(float f) {
    union { float f; unsigned int i; } v; v.f = f;
    unsigned int lsb = (v.i >> 16) & 1u;
    v.i += 0x7fffu + lsb;                 // round-nearest-even
    return (unsigned short)(v.i >> 16);
}

// ---------------- utility ----------------
__global__ void zero32_kernel(unsigned int* __restrict__ p, int n) {
    int i = blockIdx.x * blockDim.x + threadIdx.x;
    if (i < n) p[i] = 0u;
}

// ---------------- batched graph prep (all 4 snapshots in one pass) ----------------
// hist over 4E edges; deg4 is 4 disjoint per-snapshot regions; slot = within-row position
__global__ void hist4_kernel(const int* __restrict__ ei, int* __restrict__ deg4,
        int* __restrict__ slot4) {
    int i = blockIdx.x * 256 + threadIdx.x;          // grid covers E4 exactly
    int s = i / E_EDGES;
    int j = i - s * E_EDGES;
    int d = ei[(size_t)s * 2 * E_EDGES + E_EDGES + j];
    slot4[i] = atomicAdd(&deg4[s * N_NODES + d], 1);
}

// scan phase 1 over deg4[4N]: block = 1024 elems (int4/thread); also emits dinv4
__global__ __launch_bounds__(256) void scan_part4_kernel(const int* __restrict__ deg4,
        int* __restrict__ bsum, float* __restrict__ dinv4) {
    __shared__ int red[4];
    int base = blockIdx.x * 1024 + threadIdx.x * 4;
    int4 v = make_int4(0, 0, 0, 0);
    if (base < N4) {                                  // N4 % 4 == 0: all-or-nothing
        v = *(const int4*)(deg4 + base);
        dinv4[base + 0] = rsqrtf((float)(v.x + 1));   // +1 self-loop
        dinv4[base + 1] = rsqrtf((float)(v.y + 1));
        dinv4[base + 2] = rsqrtf((float)(v.z + 1));
        dinv4[base + 3] = rsqrtf((float)(v.w + 1));
    }
    int t = v.x + v.y + v.z + v.w;
    #pragma unroll
    for (int off = 32; off > 0; off >>= 1) t += __shfl_down(t, off, 64);
    int wave = threadIdx.x >> 6, lane = threadIdx.x & 63;
    if (lane == 0) red[wave] = t;
    __syncthreads();
    if (threadIdx.x == 0) bsum[blockIdx.x] = red[0] + red[1] + red[2] + red[3];
}

__global__ __launch_bounds__(512) void scan_top_kernel(const int* __restrict__ bsum,
        int* __restrict__ boff) {
    __shared__ int s[512];
    int t = threadIdx.x;
    s[t] = (t < NBLK4) ? bsum[t] : 0;
    __syncthreads();
    for (int off = 1; off < 512; off <<= 1) {
        int v = (t >= off) ? s[t - off] : 0;
        __syncthreads();
        s[t] += v;
        __syncthreads();
    }
    if (t < NBLK4) boff[t] = (t == 0) ? 0 : s[t - 1];
}

// phase 3: global exclusive scan -> rowptr4[4N+1]; snapshot s's rows carry +s*E offset
// automatically (each snapshot contributes exactly E edges)
__global__ __launch_bounds__(256) void scan_fin4_kernel(const int* __restrict__ deg4,
        const int* __restrict__ boff, int* __restrict__ rowptr4) {
    __shared__ int sh[256];
    int base = blockIdx.x * 1024 + threadIdx.x * 4;
    int4 v = make_int4(0, 0, 0, 0);
    if (base < N4) v = *(const int4*)(deg4 + base);
    int tsum = v.x + v.y + v.z + v.w;
    sh[threadIdx.x] = tsum;
    __syncthreads();
    for (int off = 1; off < 256; off <<= 1) {
        int u = (threadIdx.x >= off) ? sh[threadIdx.x - off] : 0;
        __syncthreads();
        sh[threadIdx.x] += u;
        __syncthreads();
    }
    int excl = boff[blockIdx.x] + sh[threadIdx.x] - tsum;
    if (base < N4) {
        int4 o;
        o.x = excl;
        o.y = excl + v.x;
        o.z = excl + v.x + v.y;
        o.w = excl + v.x + v.y + v.z;
        *(int4*)(rowptr4 + base) = o;
    }
    if (base == 0) rowptr4[N4] = E4;
}

// binned, atomic-free CSR fill over all 4E edges (bin regions stay L2-resident)
__global__ __launch_bounds__(256) void fill4_kernel(const int* __restrict__ ei,
        const int* __restrict__ slot4, const int* __restrict__ rowptr4,
        int* __restrict__ csrsrc4) {
    int chunk = blockIdx.x >> 3;
    int bin = blockIdx.x & (NBIN - 1);
    int lo = bin * BIN_W, hi = lo + BIN_W;
    int base = chunk * FILL_CHUNK + threadIdx.x;
    #pragma unroll
    for (int k = 0; k < FILL_CHUNK / 256; ++k) {
        int i = base + k * 256;
        if (i < E4) {
            int s = i / E_EDGES;
            int j = i - s * E_EDGES;
            int d = ei[(size_t)s * 2 * E_EDGES + E_EDGES + j];
            if (d >= lo && d < hi) {
                int sc = ei[(size_t)s * 2 * E_EDGES + j];
                csrsrc4[rowptr4[s * N_NODES + d] + slot4[i]] = sc;
            }
        }
    }
}

// ------- MFMA GEMM (once per call): xw1 = x @ W1, bf16 out -------
// Layouts (HW-verified r8): A[m=lane&15][k=quad*8+j]; B[k][n=lane&15]; C/D col=lane&15,row=quad*4+reg
__global__ __launch_bounds__(256) void gemm_xw1_mfma(const float* __restrict__ A,
        const float* __restrict__ B, unsigned short* __restrict__ C, int M) {
    __shared__ unsigned short As[64][136];   // [m][k], +8 pad
    __shared__ unsigned short Bs[64][136];   // [n][k]
    int tid = threadIdx.x;
    int m0 = blockIdx.x * 64, n0 = blockIdx.y * 64;
    {
        int row = tid >> 2, c0 = (tid & 3) * 32;
        int gm = m0 + row;
        #pragma unroll
        for (int i = 0; i < 8; ++i) {
            float4 v = make_float4(0.f, 0.f, 0.f, 0.f);
            if (gm < M) v = *(const float4*)(A + (size_t)gm * D_IN + c0 + i * 4);
            As[row][c0 + i * 4 + 0] = f2bf(v.x);
            As[row][c0 + i * 4 + 1] = f2bf(v.y);
            As[row][c0 + i * 4 + 2] = f2bf(v.z);
            As[row][c0 + i * 4 + 3] = f2bf(v.w);
        }
    }
    {
        int k = tid >> 1, nb = (tid & 1) * 32;
        #pragma unroll
        for (int i = 0; i < 8; ++i) {
            float4 v = *(const float4*)(B + (size_t)k * H_DIM + n0 + nb + i * 4);
            Bs[nb + i * 4 + 0][k] = f2bf(v.x);
            Bs[nb + i * 4 + 1][k] = f2bf(v.y);
            Bs[nb + i * 4 + 2][k] = f2bf(v.z);
            Bs[nb + i * 4 + 3][k] = f2bf(v.w);
        }
    }
    __syncthreads();
    int w = tid >> 6, l = tid & 63;
    int q = l >> 4, mrow = l & 15;
    f32x4 acc[4] = {{0.f,0.f,0.f,0.f},{0.f,0.f,0.f,0.f},{0.f,0.f,0.f,0.f},{0.f,0.f,0.f,0.f}};
    #pragma unroll
    for (int kk = 0; kk < 4; ++kk) {
        bf16x8 a = *(const bf16x8*)&As[16 * w + mrow][kk * 32 + q * 8];
        #pragma unroll
        for (int ct = 0; ct < 4; ++ct) {
            bf16x8 b = *(const bf16x8*)&Bs[ct * 16 + mrow][kk * 32 + q * 8];
            acc[ct] = __builtin_amdgcn_mfma_f32_16x16x32_bf16(a, b, acc[ct], 0, 0, 0);
        }
    }
    #pragma unroll
    for (int ct = 0; ct < 4; ++ct) {
        int col = n0 + ct * 16 + mrow;
        #pragma unroll
        for (int i = 0; i < 4; ++i) {
            int m = m0 + 16 * w + q * 4 + i;
            if (m < M) C[(size_t)m * H_DIM + col] = f2bf(acc[ct][i]);
        }
    }
}

// ------- SpMM layer 0 (fused bias+relu), 4-way edge unroll (r7/r9-proven: VGPR 20) -------
// soff = s*N selects the snapshot's rowptr/dinv region; csrsrc indices are global
__global__ __launch_bounds__(256) void spmm_l0_kernel(const unsigned short* __restrict__ xw1,
        const float* __restrict__ dinv4, const int* __restrict__ rowptr4,
        const int* __restrict__ csrsrc4, const float* __restrict__ b1,
        unsigned short* __restrict__ h, int soff) {
    int r = (blockIdx.x << 2) + (threadIdx.x >> 6);
    int lane = threadIdx.x & 63;
    int rg = soff + r;
    int e0 = rowptr4[rg], e1 = rowptr4[rg + 1];
    float di = dinv4[rg];
    float4 acc = make_float4(0.f, 0.f, 0.f, 0.f);
    const ushort4* tp = (const ushort4*)xw1;
    const float* dv = dinv4 + soff;
    int e = e0;
    for (; e + 4 <= e1; e += 4) {
        int s0 = csrsrc4[e], s1 = csrsrc4[e + 1], s2 = csrsrc4[e + 2], s3 = csrsrc4[e + 3];
        float w0 = dv[s0] * di, w1 = dv[s1] * di, w2 = dv[s2] * di, w3 = dv[s3] * di;
        ushort4 u0 = tp[(size_t)s0 * 64 + lane];
        ushort4 u1 = tp[(size_t)s1 * 64 + lane];
        ushort4 u2 = tp[(size_t)s2 * 64 + lane];
        ushort4 u3 = tp[(size_t)s3 * 64 + lane];
        acc.x = fmaf(bf2f(u0.x), w0, acc.x); acc.y = fmaf(bf2f(u0.y), w0, acc.y);
        acc.z = fmaf(bf2f(u0.z), w0, acc.z); acc.w = fmaf(bf2f(u0.w), w0, acc.w);
        acc.x = fmaf(bf2f(u1.x), w1, acc.x); acc.y = fmaf(bf2f(u1.y), w1, acc.y);
        acc.z = fmaf(bf2f(u1.z), w1, acc.z); acc.w = fmaf(bf2f(u1.w), w1, acc.w);
        acc.x = fmaf(bf2f(u2.x), w2, acc.x); acc.y = fmaf(bf2f(u2.y), w2, acc.y);
        acc.z = fmaf(bf2f(u2.z), w2, acc.z); acc.w = fmaf(bf2f(u2.w), w2, acc.w);
        acc.x = fmaf(bf2f(u3.x), w3, acc.x); acc.y = fmaf(bf2f(u3.y), w3, acc.y);
        acc.z = fmaf(bf2f(u3.z), w3, acc.z); acc.w = fmaf(bf2f(u3.w), w3, acc.w);
    }
    for (; e < e1; ++e) {
        int s = csrsrc4[e];
        float wv = dv[s] * di;
        ushort4 u = tp[(size_t)s * 64 + lane];
        acc.x = fmaf(bf2f(u.x), wv, acc.x); acc.y = fmaf(bf2f(u.y), wv, acc.y);
        acc.z = fmaf(bf2f(u.z), wv, acc.z); acc.w = fmaf(bf2f(u.w), wv, acc.w);
    }
    ushort4 us = tp[(size_t)r * 64 + lane];
    float wd = di * di;
    float4 bb = ((const float4*)b1)[lane];
    ushort4 o;
    o.x = f2bf(fmaxf(fmaf(bf2f(us.x), wd, acc.x) + bb.x, 0.f));
    o.y = f2bf(fmaxf(fmaf(bf2f(us.y), wd, acc.y) + bb.y, 0.f));
    o.z = f2bf(fmaxf(fmaf(bf2f(us.z), wd, acc.z) + bb.z, 0.f));
    o.w = f2bf(fmaxf(fmaf(bf2f(us.w), wd, acc.w) + bb.w, 0.f));
    ((ushort4*)h)[(size_t)r * 64 + lane] = o;
}

// ---------------- SpMM layer 1 (post rows only) ----------------
__global__ __launch_bounds__(256) void spmm_h_post_kernel(const unsigned short* __restrict__ h,
        const float* __restrict__ dinv4, const int* __restrict__ rowptr4,
        const int* __restrict__ csrsrc4, const int* __restrict__ post,
        float* __restrict__ t1p, int soff) {
    int p = (blockIdx.x << 2) + (threadIdx.x >> 6);
    int lane = threadIdx.x & 63;
    int r = post[p];
    int rg = soff + r;
    int e0 = rowptr4[rg], e1 = rowptr4[rg + 1];
    float di = dinv4[rg];
    float4 acc = make_float4(0.f, 0.f, 0.f, 0.f);
    const ushort4* hp = (const ushort4*)h;
    const float* dv = dinv4 + soff;
    int e = e0;
    for (; e + 4 <= e1; e += 4) {
        int s0 = csrsrc4[e], s1 = csrsrc4[e + 1], s2 = csrsrc4[e + 2], s3 = csrsrc4[e + 3];
        float w0 = dv[s0] * di, w1 = dv[s1] * di, w2 = dv[s2] * di, w3 = dv[s3] * di;
        ushort4 u0 = hp[(size_t)s0 * 64 + lane];
        ushort4 u1 = hp[(size_t)s1 * 64 + lane];
        ushort4 u2 = hp[(size_t)s2 * 64 + lane];
        ushort4 u3 = hp[(size_t)s3 * 64 + lane];
        acc.x = fmaf(bf2f(u0.x), w0, acc.x); acc.y = fmaf(bf2f(u0.y), w0, acc.y);
        acc.z = fmaf(bf2f(u0.z), w0, acc.z); acc.w = fmaf(bf2f(u0.w), w0, acc.w);
        acc.x = fmaf(bf2f(u1.x), w1, acc.x); acc.y = fmaf(bf2f(u1.y), w1, acc.y);
        acc.z = fmaf(bf2f(u1.z), w1, acc.z); acc.w = fmaf(bf2f(u1.w), w1, acc.w);
        acc.x = fmaf(bf2f(u2.x), w2, acc.x); acc.y = fmaf(bf2f(u2.y), w2, acc.y);
        acc.z = fmaf(bf2f(u2.z), w2, acc.z); acc.w = fmaf(bf2f(u2.w), w2, acc.w);
        acc.x = fmaf(bf2f(u3.x), w3, acc.x); acc.y = fmaf(bf2f(u3.y), w3, acc.y);
        acc.z = fmaf(bf2f(u3.z), w3, acc.z); acc.w = fmaf(bf2f(u3.w), w3, acc.w);
    }
    for (; e < e1; ++e) {
        int s = csrsrc4[e];
        float wv = dv[s] * di;
        ushort4 u = hp[(size_t)s * 64 + lane];
        acc.x = fmaf(bf2f(u.x), wv, acc.x); acc.y = fmaf(bf2f(u.y), wv, acc.y);
        acc.z = fmaf(bf2f(u.z), wv, acc.z); acc.w = fmaf(bf2f(u.w), wv, acc.w);
    }
    ushort4 u = hp[(size_t)r * 64 + lane];
    float wd = di * di;
    acc.x = fmaf(bf2f(u.x), wd, acc.x);
    acc.y = fmaf(bf2f(u.y), wd, acc.y);
    acc.z = fmaf(bf2f(u.z), wd, acc.z);
    acc.w = fmaf(bf2f(u.w), wd, acc.w);
    ((float4*)t1p)[(size_t)p * 64 + lane] = acc;
}

// ------- MFMA GEMM layer 1 (post rows): accP += t1p @ W2 + b2 + h[post] -------
__global__ __launch_bounds__(256) void gemm_l1_mfma(const float* __restrict__ A,
        const float* __restrict__ B, const float* __restrict__ b2,
        const unsigned short* __restrict__ h, const int* __restrict__ post,
        float* __restrict__ accP, int M) {
    __shared__ unsigned short As[64][136];
    __shared__ unsigned short Bs[64][136];
    int tid = threadIdx.x;
    int m0 = blockIdx.x * 64, n0 = blockIdx.y * 64;
    int w = tid >> 6, l = tid & 63;
    int q = l >> 4, mrow = l & 15;
    f32x4 acc[4] = {{0.f,0.f,0.f,0.f},{0.f,0.f,0.f,0.f},{0.f,0.f,0.f,0.f},{0.f,0.f,0.f,0.f}};
    for (int kk = 0; kk < 256; kk += 128) {
        __syncthreads();
        {
            int row = tid >> 2, c0 = (tid & 3) * 32;
            int gm = m0 + row;
            #pragma unroll
            for (int i = 0; i < 8; ++i) {
                float4 v = make_float4(0.f, 0.f, 0.f, 0.f);
                if (gm < M) v = *(const float4*)(A + (size_t)gm * 256 + kk + c0 + i * 4);
                As[row][c0 + i * 4 + 0] = f2bf(v.x);
                As[row][c0 + i * 4 + 1] = f2bf(v.y);
                As[row][c0 + i * 4 + 2] = f2bf(v.z);
                As[row][c0 + i * 4 + 3] = f2bf(v.w);
            }
        }
        {
            int k = tid >> 1, nb = (tid & 1) * 32;
            #pragma unroll
            for (int i = 0; i < 8; ++i) {
                float4 v = *(const float4*)(B + (size_t)(kk + k) * H_DIM + n0 + nb + i * 4);
                Bs[nb + i * 4 + 0][k] = f2bf(v.x);
                Bs[nb + i * 4 + 1][k] = f2bf(v.y);
                Bs[nb + i * 4 + 2][k] = f2bf(v.z);
                Bs[nb + i * 4 + 3][k] = f2bf(v.w);
            }
        }
        __syncthreads();
        #pragma unroll
        for (int ks = 0; ks < 4; ++ks) {
            bf16x8 a = *(const bf16x8*)&As[16 * w + mrow][ks * 32 + q * 8];
            #pragma unroll
            for (int ct = 0; ct < 4; ++ct) {
                bf16x8 b = *(const bf16x8*)&Bs[ct * 16 + mrow][ks * 32 + q * 8];
                acc[ct] = __builtin_amdgcn_mfma_f32_16x16x32_bf16(a, b, acc[ct], 0, 0, 0);
            }
        }
    }
    #pragma unroll
    for (int ct = 0; ct < 4; ++ct) {
        int col = n0 + ct * 16 + mrow;
        float bias = b2[col];
        #pragma unroll
        for (int i = 0; i < 4; ++i) {
            int m = m0 + 16 * w + q * 4 + i;
            if (m < M) {
                int node = post[m];
                float hv = bf2f(h[(size_t)node * 256 + col]);
                accP[(size_t)m * 256 + col] += acc[ct][i] + bias + hv;
            }
        }
    }
}

// ---------------- classifier ----------------
__global__ __launch_bounds__(128) void classifier_kernel(const float* __restrict__ accP,
        const float* __restrict__ Wc1, const float* __restrict__ bc1,
        const float* __restrict__ Wc2, const float* __restrict__ bc2,
        float* __restrict__ out) {
    __shared__ float arow[8][256];
    __shared__ float red[2][8];
    int p0 = blockIdx.x << 3;
    int tid = threadIdx.x;
    for (int idx = tid; idx < 8 * 256; idx += 128) {
        int pl = idx >> 8, k = idx & 255;
        arow[pl][k] = 0.25f * accP[(size_t)(p0 + pl) * 256 + k];
    }
    __syncthreads();
    float s[8];
    float b = bc1[tid];
    #pragma unroll
    for (int pl = 0; pl < 8; ++pl) s[pl] = b;
    for (int k = 0; k < 256; ++k) {
        float wv = Wc1[k * 128 + tid];
        #pragma unroll
        for (int pl = 0; pl < 8; ++pl) s[pl] = fmaf(arow[pl][k], wv, s[pl]);
    }
    float wc2 = Wc2[tid];
    float part[8];
    #pragma unroll
    for (int pl = 0; pl < 8; ++pl) part[pl] = fmaxf(s[pl], 0.f) * wc2;
    #pragma unroll
    for (int off = 32; off > 0; off >>= 1)
        #pragma unroll
        for (int pl = 0; pl < 8; ++pl) part[pl] += __shfl_down(part[pl], off, 64);
    int wave = tid >> 6, lane = tid & 63;
    if (lane == 0) {
        #pragma unroll
        for (int pl = 0; pl < 8; ++pl) red[wave][pl] = part[pl];
    }
    __syncthreads();
    if (tid < 8) {
        float logit = red[0][tid] + red[1][tid] + bc2[0];
        out[p0 + tid] = 1.f / (1.f + expf(-logit));
    }
}

extern "C" void kernel_launch(void* const* d_in, const int* in_sizes, int n_in,
                              void* d_out, int out_size, void* d_ws, size_t ws_size,
                              hipStream_t stream) {
    const float* x   = (const float*)d_in[0];
    const int*   ei  = (const int*)d_in[1];
    const int*   post= (const int*)d_in[2];
    const float* W1  = (const float*)d_in[3];
    const float* b1  = (const float*)d_in[4];
    const float* W2  = (const float*)d_in[5];
    const float* b2  = (const float*)d_in[6];
    const float* Wc1 = (const float*)d_in[7];
    const float* bc1 = (const float*)d_in[8];
    const float* Wc2 = (const float*)d_in[9];
    const float* bc2 = (const float*)d_in[10];
    float* out = (float*)d_out;

    char* w = (char*)d_ws;
    size_t off = 0;
#define WS_ALLOC(type, name, count) \
    type* name = (type*)(w + off); \
    off += (((size_t)(count) * sizeof(type)) + 255) & ~(size_t)255;
    WS_ALLOC(unsigned short, xw1,     (size_t)N_NODES * H_DIM)   // 51.2 MB (bf16)
    WS_ALLOC(unsigned short, hbuf,    (size_t)N_NODES * H_DIM)   // 51.2 MB (slot4 aliases this)
    WS_ALLOC(float,          t1p,     (size_t)P_POST * H_DIM)    // 10.24 MB
    WS_ALLOC(float,          accP,    (size_t)P_POST * H_DIM)    // 10.24 MB (exact 256-mult)
    WS_ALLOC(int,            deg4,    N4)                        // 1.6 MB — MUST follow accP
    WS_ALLOC(float,          dinv4,   N4)                        // 1.6 MB
    WS_ALLOC(int,            rowptr4, N4 + 4)                    // 1.6 MB
    WS_ALLOC(int,            csrsrc4, E4)                        // 25.6 MB
    WS_ALLOC(int,            bsum,    NBLK4)
    WS_ALLOC(int,            boff,    NBLK4)
#undef WS_ALLOC
    // slot4[E4] (25.6 MB) aliases hbuf (51.2 MB): slot dead before spmm_l0 writes h
    int* slot4 = (int*)hbuf;                         // total ws ~153 MB
    (void)ws_size; (void)in_sizes; (void)n_in; (void)out_size;

    // accP (10,240,000 B = exact multiple of 256) is contiguous with deg4 -> one zero launch
    zero32_kernel<<<(P_POST * H_DIM + N4 + 255) / 256, 256, 0, stream>>>(
        (unsigned int*)accP, P_POST * H_DIM + N4);

    // ---- batched prep for all 4 snapshots (6 launches total, was 24) ----
    hist4_kernel<<<E4 / 256, 256, 0, stream>>>(ei, deg4, slot4);
    scan_part4_kernel<<<NBLK4, 256, 0, stream>>>(deg4, bsum, dinv4);
    scan_top_kernel<<<1, 512, 0, stream>>>(bsum, boff);
    scan_fin4_kernel<<<NBLK4, 256, 0, stream>>>(deg4, boff, rowptr4);
    fill4_kernel<<<FILL_NCHUNK * NBIN, 256, 0, stream>>>(ei, slot4, rowptr4, csrsrc4);

    // xw1 = x @ W1 once per call (snapshot-invariant) — bf16 MFMA
    dim3 gg((N_NODES + 63) / 64, H_DIM / 64);
    gemm_xw1_mfma<<<gg, 256, 0, stream>>>(x, W1, xw1, N_NODES);

    for (int s = 0; s < S_SNAP; ++s) {
        int soff = s * N_NODES;
        // h = relu(Ahat @ xw1 + b1)   [N,256] bf16   (overwrites slot4 region — dead)
        spmm_l0_kernel<<<N_NODES / 4, 256, 0, stream>>>(xw1, dinv4, rowptr4, csrsrc4,
                                                        b1, hbuf, soff);
        // t1p = (Ahat @ h)[post]   [P,256] fp32
        spmm_h_post_kernel<<<P_POST / 4, 256, 0, stream>>>(hbuf, dinv4, rowptr4, csrsrc4,
                                                           post, t1p, soff);
        // accP += t1p @ W2 + b2 + h[post]   — bf16 MFMA
        dim3 g1((P_POST + 63) / 64, H_DIM / 64);
        gemm_l1_mfma<<<g1, 256, 0, stream>>>(t1p, W2, b2, hbuf, post, accP, P_POST);
    }
    classifier_kernel<<<P_POST / 8, 128, 0, stream>>>(accP, Wc1, bc1, Wc2, bc2, out);
}